// Round 13
// baseline (1689.568 us; speedup 1.0000x reference)
//
#include <hip/hip_runtime.h>
#include <cstdint>
#include <type_traits>

#define B_    8
#define T_    2048
#define C_    1024
#define E_    8
#define K_    2
#define CAP_  4096
#define H_    4096
#define NTOK  (B_ * T_)      // 16384
#define NSLOT (NTOK * K_)    // 32768
#define KR_   3072           // exact router split-GEMM K: [x_hi | x_lo | x_hi]
#define MARGIN_ 3e-2f        // 8.7 sigma of approx-path logit-gap error (3.4e-3 rms)
#define FIXCAP 8192          // hfix capacity (rows); flag rate est ~25% => ~4-5.5k

typedef __bf16    bf16x8 __attribute__((ext_vector_type(8)));
typedef _Float16  half8  __attribute__((ext_vector_type(8)));
typedef float     f32x4  __attribute__((ext_vector_type(4)));

#define AS1 __attribute__((address_space(1)))
#define AS3 __attribute__((address_space(3)))

static __device__ __forceinline__ float b2f(unsigned short u) {
    union { float f; unsigned int i; } v; v.i = ((unsigned int)u) << 16; return v.f;
}
static __device__ __forceinline__ unsigned short f2b(float f) {
    unsigned int x = __float_as_uint(f);
    unsigned int r = (x + 0x7fffu + ((x >> 16) & 1u)) >> 16;   // RNE
    return (unsigned short)r;
}
static __device__ __forceinline__ unsigned short f2h(float f) {
    _Float16 h = (_Float16)f;                                   // RNE
    return __builtin_bit_cast(unsigned short, h);
}

template<int W> static __device__ __forceinline__ void vm_wait() {
    if constexpr (W == 4) asm volatile("s_waitcnt vmcnt(4)" ::: "memory");
    else if constexpr (W == 0) asm volatile("s_waitcnt vmcnt(0)" ::: "memory");
}

// ---------------------------------------------------------------------------
// 8-phase MFMA GEMM (round-9/12 proven schedule — K-loop byte-identical):
// 256x256 tile, BK=64, 512 threads (8 waves 2Mx4N), 2 LDS dbufs (128 KiB).
// Counted vmcnt(4) never 0 mid-loop; WAR/RAW ledger per round-9 derivation.
// F16: fp16 operands (mfma_f32_16x16x32_f16).
// EPI=0: normal store (f32 or bf16 via TC).
// EPI=1: selective-exact router pass — early-exit if bm >= *cnt; stores f32
//        COMPACT rows r < *cnt to Cout[r][:] (Cout = hfix).
// EPI=2: fused MoE combine — s = slotof[z*CAP+r]; if s>=0:
//        atomicAdd(y[(s>>1)*Nld+c], v*probs[s]). <=2 commutative adds per
//        element from 0 => bitwise deterministic.
// NOTE: 2 waves/SIMD structural (acc=128 regs); min-waves stays 2 (round-7:
// 4 -> acc spill -> 6x slower).
// ---------------------------------------------------------------------------
template<int RELU, typename TC, bool F16, int EPI>
__global__ __launch_bounds__(512, 2) void gemm256_8ph(
    const unsigned short* __restrict__ A, const unsigned short* __restrict__ BT,
    const float* __restrict__ bias, TC* __restrict__ Cout,
    int Kd, int Nld, int NT,
    long sA, long sB, long sBias, long sC,
    const int* __restrict__ cnt, const int* __restrict__ slotof,
    const float* __restrict__ probsv, float* __restrict__ yout)
{
    extern __shared__ char smem[];   // dbuf d: A at d*65536, B at d*65536+32768

    const int z = blockIdx.z;
    A    += (size_t)z * sA;
    BT   += (size_t)z * sB;
    bias += (size_t)z * sBias;
    Cout += (size_t)z * sC;

    // XCD-aware swizzle (nwg % 8 == 0 for all our grids)
    const int gx = gridDim.x;
    const int nwg = gx * gridDim.y;
    int wg = blockIdx.y * gx + blockIdx.x;
    wg = (wg & 7) * (nwg >> 3) + (wg >> 3);
    const int bm = (wg / gx) * 256;
    const int bn = (wg % gx) * 256;

    int nf = 0;
    if constexpr (EPI == 1) {
        nf = *cnt;
        if (bm >= nf) return;        // uniform per-block, before any barrier
    }

    const int tid  = threadIdx.x;
    const int lane = tid & 63;
    const int wid  = tid >> 6;
    const int wrow = (wid >> 2) * 128;   // wave M offset (2 waves in M)
    const int wcol = (wid & 3) * 64;     // wave N offset (4 waves in N)
    const int fr = lane & 15;            // fragment row/col within 16
    const int fq = lane >> 4;            // k-chunk selector (0..3)

    const size_t rbA = (size_t)Kd * 2;   // row stride in bytes (A and BT)
    const char* Ag = (const char*)A  + (size_t)bm * rbA;
    const char* Bg = (const char*)BT + (size_t)bn * rbA;

    f32x4 acc[8][4];
#pragma unroll
    for (int i = 0; i < 8; i++)
#pragma unroll
        for (int j = 0; j < 4; j++) acc[i][j] = (f32x4){0.f, 0.f, 0.f, 0.f};

    auto STAGE_A = [&](int kt) {
        char* d = smem + (size_t)(kt & 1) * 65536;
        const size_t kb = (size_t)kt * 128;
#pragma unroll
        for (int r = 0; r < 4; ++r) {
            const int o    = r * 8192 + tid * 16;
            const int row  = o >> 7;
            const int slot = (o >> 4) & 7;
            const int ss   = (slot ^ (row & 7)) << 4;
            __builtin_amdgcn_global_load_lds(
                (const AS1 void*)(Ag + (size_t)row * rbA + kb + ss),
                (AS3 void*)(d + r * 8192 + wid * 1024), 16, 0, 0);
        }
    };
    auto STAGE_B = [&](int kt) {
        char* d = smem + (size_t)(kt & 1) * 65536 + 32768;
        const size_t kb = (size_t)kt * 128;
#pragma unroll
        for (int r = 0; r < 4; ++r) {
            const int o    = r * 8192 + tid * 16;
            const int row  = o >> 7;
            const int slot = (o >> 4) & 7;
            const int ss   = (slot ^ (row & 7)) << 4;
            __builtin_amdgcn_global_load_lds(
                (const AS1 void*)(Bg + (size_t)row * rbA + kb + ss),
                (AS3 void*)(d + r * 8192 + wid * 1024), 16, 0, 0);
        }
    };

    auto LDA = [&](int kt, int mi, int kk) -> bf16x8 {
        const char* base = smem + (size_t)(kt & 1) * 65536;
        const int row  = wrow + mi * 16 + fr;
        const int slot = (kk * 4 + fq) ^ (row & 7);
        return *(const bf16x8*)(base + row * 128 + slot * 16);
    };
    auto LDB = [&](int kt, int ni, int kk) -> bf16x8 {
        const char* base = smem + (size_t)(kt & 1) * 65536 + 32768;
        const int row  = wcol + ni * 16 + fr;
        const int slot = (kk * 4 + fq) ^ (row & 7);
        return *(const bf16x8*)(base + row * 128 + slot * 16);
    };
    auto MFMA = [&](f32x4 c, bf16x8 a, bf16x8 b) -> f32x4 {
        if constexpr (F16)
            return __builtin_amdgcn_mfma_f32_16x16x32_f16(
                __builtin_bit_cast(half8, a), __builtin_bit_cast(half8, b), c, 0, 0, 0);
        else
            return __builtin_amdgcn_mfma_f32_16x16x32_bf16(a, b, c, 0, 0, 0);
    };

    // ---- prologue
    STAGE_A(0); STAGE_B(0); STAGE_B(1);
    vm_wait<4>();
    __builtin_amdgcn_s_barrier();

    bf16x8 a[4], bb[4];
    for (int kt = 0; kt < NT; ++kt) {
        // ---------- ph0
#pragma unroll
        for (int i = 0; i < 4; ++i) a[i]  = LDA(kt, i, 0);
#pragma unroll
        for (int i = 0; i < 4; ++i) bb[i] = LDB(kt, i, 0);
        if (kt + 1 < NT) STAGE_A(kt + 1);
        __builtin_amdgcn_s_barrier();
        __builtin_amdgcn_s_setprio(1);
#pragma unroll
        for (int mi = 0; mi < 4; ++mi)
#pragma unroll
            for (int ni = 0; ni < 4; ++ni)
                acc[mi][ni] = MFMA(acc[mi][ni], a[mi], bb[ni]);
        __builtin_amdgcn_s_setprio(0);
        __builtin_amdgcn_s_barrier();
        // ---------- ph1
#pragma unroll
        for (int i = 0; i < 4; ++i) a[i] = LDA(kt, 4 + i, 0);
        __builtin_amdgcn_s_barrier();
        __builtin_amdgcn_s_setprio(1);
#pragma unroll
        for (int mi = 0; mi < 4; ++mi)
#pragma unroll
            for (int ni = 0; ni < 4; ++ni)
                acc[4 + mi][ni] = MFMA(acc[4 + mi][ni], a[mi], bb[ni]);
        __builtin_amdgcn_s_setprio(0);
        __builtin_amdgcn_s_barrier();
        // ---------- ph2
#pragma unroll
        for (int i = 0; i < 4; ++i) a[i]  = LDA(kt, i, 1);
#pragma unroll
        for (int i = 0; i < 4; ++i) bb[i] = LDB(kt, i, 1);
        __builtin_amdgcn_s_barrier();
        __builtin_amdgcn_s_setprio(1);
#pragma unroll
        for (int mi = 0; mi < 4; ++mi)
#pragma unroll
            for (int ni = 0; ni < 4; ++ni)
                acc[mi][ni] = MFMA(acc[mi][ni], a[mi], bb[ni]);
        __builtin_amdgcn_s_setprio(0);
        __builtin_amdgcn_s_barrier();
        // ---------- ph3
#pragma unroll
        for (int i = 0; i < 4; ++i) a[i] = LDA(kt, 4 + i, 1);
        if (kt + 2 < NT) STAGE_B(kt + 2);
        if (kt + 1 < NT) {
            if (kt + 2 < NT) vm_wait<4>();
            else             vm_wait<0>();
        }
        __builtin_amdgcn_s_barrier();
        __builtin_amdgcn_s_setprio(1);
#pragma unroll
        for (int mi = 0; mi < 4; ++mi)
#pragma unroll
            for (int ni = 0; ni < 4; ++ni)
                acc[4 + mi][ni] = MFMA(acc[4 + mi][ni], a[mi], bb[ni]);
        __builtin_amdgcn_s_setprio(0);
        __builtin_amdgcn_s_barrier();
    }

    // ---- epilogue (16x16 C/D: col=lane&15, row=fq*4+reg — round-6 proven).
    const float* bias_o = bias;
    asm volatile("" : "+s"(bias_o));
#pragma unroll
    for (int mi = 0; mi < 8; ++mi) {
#pragma unroll
        for (int ni = 0; ni < 4; ++ni) {
            const int c = bn + wcol + ni * 16 + fr;
            const float bv = bias_o[c];
#pragma unroll
            for (int rg = 0; rg < 4; ++rg) {
                const int r = bm + wrow + mi * 16 + fq * 4 + rg;
                float v = acc[mi][ni][rg] + bv;
                if (RELU) v = fmaxf(v, 0.f);
                if constexpr (EPI == 1) {
                    if (r < nf)
                        ((float*)Cout)[(size_t)r * Nld + c] = v;
                } else if constexpr (EPI == 2) {
                    const int s = slotof[z * CAP_ + r];
                    if (s >= 0)
                        atomicAdd(yout + (size_t)(s >> 1) * Nld + c, v * probsv[s]);
                } else if constexpr (std::is_same_v<TC, float>) {
                    Cout[(size_t)r * Nld + c] = v;
                } else {
                    Cout[(size_t)r * Nld + c] = f2b(v);
                }
            }
        }
    }
}

// ---------------------------------------------------------------------------
// x (fp32) -> fp16 [NTOK][1024] for the approx router pass
// ---------------------------------------------------------------------------
__global__ __launch_bounds__(256) void split_x16(
    const float* __restrict__ x, unsigned short* __restrict__ x16)
{
    const int n = blockIdx.x;
    const int c = threadIdx.x * 4;
    const float4 v = *(const float4*)(x + (size_t)n * C_ + c);
    ushort4 u;
    u.x = f2h(v.x); u.y = f2h(v.y); u.z = f2h(v.z); u.w = f2h(v.w);
    *(ushort4*)(x16 + (size_t)n * C_ + c) = u;
}

// ---------------------------------------------------------------------------
// Gather flagged tokens' 3-term split rows: Axc[i] = [x_hi | x_lo | x_hi]
// ---------------------------------------------------------------------------
__global__ __launch_bounds__(256) void gather_split(
    const float* __restrict__ x, const int* __restrict__ list,
    const int* __restrict__ count, unsigned short* __restrict__ Axc)
{
    const int i = blockIdx.x;
    if (i >= *count) return;
    const int n = list[i];
    const int c = threadIdx.x * 4;
    const float4 v = *(const float4*)(x + (size_t)n * C_ + c);
    ushort4 hi, lo;
    hi.x = f2b(v.x); lo.x = f2b(v.x - b2f(hi.x));
    hi.y = f2b(v.y); lo.y = f2b(v.y - b2f(hi.y));
    hi.z = f2b(v.z); lo.z = f2b(v.z - b2f(hi.z));
    hi.w = f2b(v.w); lo.w = f2b(v.w - b2f(hi.w));
    unsigned short* row = Axc + (size_t)i * KR_;
    *(ushort4*)(row + c)          = hi;
    *(ushort4*)(row + C_ + c)     = lo;
    *(ushort4*)(row + 2 * C_ + c) = hi;
}

// ---------------------------------------------------------------------------
// Split+transpose rw1 [C][H] fp32 -> B'^T bf16 [H][3072] = [w_hi | w_hi | w_lo]
// ---------------------------------------------------------------------------
__global__ __launch_bounds__(256) void split_w(
    const float* __restrict__ in, unsigned short* __restrict__ out)
{
    __shared__ float t[32][33];
    const int rb = blockIdx.y * 32;
    const int cb = blockIdx.x * 32;
    const int tr = threadIdx.x >> 3, tc = (threadIdx.x & 7) * 4;
    const float4 v = *(const float4*)(in + (size_t)(rb + tr) * H_ + cb + tc);
    t[tr][tc + 0] = v.x; t[tr][tc + 1] = v.y; t[tr][tc + 2] = v.z; t[tr][tc + 3] = v.w;
    __syncthreads();
    ushort4 hi, lo;
    float f;
    f = t[tc + 0][tr]; hi.x = f2b(f); lo.x = f2b(f - b2f(hi.x));
    f = t[tc + 1][tr]; hi.y = f2b(f); lo.y = f2b(f - b2f(hi.y));
    f = t[tc + 2][tr]; hi.z = f2b(f); lo.z = f2b(f - b2f(hi.z));
    f = t[tc + 3][tr]; hi.w = f2b(f); lo.w = f2b(f - b2f(hi.w));
    unsigned short* row = out + (size_t)(cb + tr) * KR_;
    *(ushort4*)(row + rb + tc)           = hi;
    *(ushort4*)(row + C_ + rb + tc)      = hi;
    *(ushort4*)(row + 2 * C_ + rb + tc)  = lo;
}

// ---------------------------------------------------------------------------
// Tiled transpose + convert: in [z][R][Ncols] f32 -> out [z][Ncols][R]
// ---------------------------------------------------------------------------
template<bool H16>
__global__ __launch_bounds__(256) void transpose_cvt(
    const float* __restrict__ in, unsigned short* __restrict__ out, int R, int Ncols)
{
    __shared__ float t[32][33];
    const size_t zoff = (size_t)blockIdx.z * R * Ncols;
    in  += zoff;
    out += zoff;
    const int rb = blockIdx.y * 32, cb = blockIdx.x * 32;
    const int tr = threadIdx.x >> 3, tc = (threadIdx.x & 7) * 4;
    const float4 v = *(const float4*)(in + (size_t)(rb + tr) * Ncols + cb + tc);
    t[tr][tc + 0] = v.x; t[tr][tc + 1] = v.y; t[tr][tc + 2] = v.z; t[tr][tc + 3] = v.w;
    __syncthreads();
    ushort4 u;
    if constexpr (H16) {
        u.x = f2h(t[tc + 0][tr]); u.y = f2h(t[tc + 1][tr]);
        u.z = f2h(t[tc + 2][tr]); u.w = f2h(t[tc + 3][tr]);
    } else {
        u.x = f2b(t[tc + 0][tr]); u.y = f2b(t[tc + 1][tr]);
        u.z = f2b(t[tc + 2][tr]); u.w = f2b(t[tc + 3][tr]);
    }
    *(ushort4*)(out + (size_t)(cb + tr) * R + rb + tc) = u;
}

// ---------------------------------------------------------------------------
// Approx router GEMM2 (h1 bf16) + top-3 + softmax(top-2) + near-tie flagging.
// iofn[n] = compact index if flagged else -1 (written for ALL n; no memset).
// ---------------------------------------------------------------------------
__global__ __launch_bounds__(256) void router_topk_approx(
    const unsigned short* __restrict__ h1, const float* __restrict__ rw2,
    const float* __restrict__ rb2, int* __restrict__ ids, float* __restrict__ probs,
    int* __restrict__ iofn, int* __restrict__ list, int* __restrict__ count)
{
    const int n = blockIdx.x;
    const unsigned short* hrow = h1 + (size_t)n * H_;
    float acc[E_];
#pragma unroll
    for (int e = 0; e < E_; e++) acc[e] = 0.f;
    const int i0 = threadIdx.x * 16;   // 256 thr x 16 = 4096 = H
#pragma unroll
    for (int c4 = 0; c4 < 16; c4 += 4) {
        const ushort4 u = *(const ushort4*)(hrow + i0 + c4);
        const float hv0 = b2f(u.x), hv1 = b2f(u.y), hv2 = b2f(u.z), hv3 = b2f(u.w);
        const float hvv[4] = {hv0, hv1, hv2, hv3};
#pragma unroll
        for (int k = 0; k < 4; ++k) {
            const float hv = hvv[k];
            const float4 w0 = *(const float4*)(rw2 + (size_t)(i0 + c4 + k) * E_);
            const float4 w1 = *(const float4*)(rw2 + (size_t)(i0 + c4 + k) * E_ + 4);
            acc[0] = fmaf(hv, w0.x, acc[0]); acc[1] = fmaf(hv, w0.y, acc[1]);
            acc[2] = fmaf(hv, w0.z, acc[2]); acc[3] = fmaf(hv, w0.w, acc[3]);
            acc[4] = fmaf(hv, w1.x, acc[4]); acc[5] = fmaf(hv, w1.y, acc[5]);
            acc[6] = fmaf(hv, w1.z, acc[6]); acc[7] = fmaf(hv, w1.w, acc[7]);
        }
    }
    __shared__ float red[E_][256];
#pragma unroll
    for (int e = 0; e < E_; e++) red[e][threadIdx.x] = acc[e];
    __syncthreads();
    for (int st = 128; st > 0; st >>= 1) {
        if (threadIdx.x < st) {
#pragma unroll
            for (int e = 0; e < E_; e++) red[e][threadIdx.x] += red[e][threadIdx.x + st];
        }
        __syncthreads();
    }
    if (threadIdx.x == 0) {
        float v1 = -1e30f, v2 = -1e30f, v3 = -1e30f; int i1 = 0, i2 = 0;
#pragma unroll
        for (int e = 0; e < E_; e++) {
            const float v = red[e][0] + rb2[e];
            if (v > v1)      { v3 = v2; v2 = v1; i2 = i1; v1 = v; i1 = e; }
            else if (v > v2) { v3 = v2; v2 = v;  i2 = e; }
            else if (v > v3) { v3 = v; }
        }
        const float e2 = expf(v2 - v1);
        const float inv = 1.f / (1.f + e2);
        ids[n * 2] = i1;  ids[n * 2 + 1] = i2;
        probs[n * 2] = inv; probs[n * 2 + 1] = e2 * inv;
        int idx = -1;
        if ((v1 - v2 < MARGIN_) || (v2 - v3 < MARGIN_)) {
            idx = atomicAdd(count, 1);
            list[idx] = n;
        }
        iofn[n] = idx;
    }
}

// ---------------------------------------------------------------------------
// Exact fixup: recompute top-2 for flagged tokens from compact exact f32 rows.
// ---------------------------------------------------------------------------
__global__ __launch_bounds__(256) void router_topk_fix(
    const float* __restrict__ hfix, const float* __restrict__ rw2,
    const float* __restrict__ rb2, int* __restrict__ ids, float* __restrict__ probs,
    const int* __restrict__ iofn)
{
    const int n = blockIdx.x;
    const int i = iofn[n];
    if (i < 0) return;
    const float* hrow = hfix + (size_t)i * H_;
    float acc[E_];
#pragma unroll
    for (int e = 0; e < E_; e++) acc[e] = 0.f;
    const int i0 = threadIdx.x * 16;
#pragma unroll
    for (int c4 = 0; c4 < 16; c4 += 4) {
        const float4 h4 = *(const float4*)(hrow + i0 + c4);
        const float hvv[4] = {h4.x, h4.y, h4.z, h4.w};
#pragma unroll
        for (int k = 0; k < 4; ++k) {
            const float hv = hvv[k];
            const float4 w0 = *(const float4*)(rw2 + (size_t)(i0 + c4 + k) * E_);
            const float4 w1 = *(const float4*)(rw2 + (size_t)(i0 + c4 + k) * E_ + 4);
            acc[0] = fmaf(hv, w0.x, acc[0]); acc[1] = fmaf(hv, w0.y, acc[1]);
            acc[2] = fmaf(hv, w0.z, acc[2]); acc[3] = fmaf(hv, w0.w, acc[3]);
            acc[4] = fmaf(hv, w1.x, acc[4]); acc[5] = fmaf(hv, w1.y, acc[5]);
            acc[6] = fmaf(hv, w1.z, acc[6]); acc[7] = fmaf(hv, w1.w, acc[7]);
        }
    }
    __shared__ float red[E_][256];
#pragma unroll
    for (int e = 0; e < E_; e++) red[e][threadIdx.x] = acc[e];
    __syncthreads();
    for (int st = 128; st > 0; st >>= 1) {
        if (threadIdx.x < st) {
#pragma unroll
            for (int e = 0; e < E_; e++) red[e][threadIdx.x] += red[e][threadIdx.x + st];
        }
        __syncthreads();
    }
    if (threadIdx.x == 0) {
        float v1 = -1e30f, v2 = -1e30f; int i1 = 0, i2 = 0;
#pragma unroll
        for (int e = 0; e < E_; e++) {
            const float v = red[e][0] + rb2[e];
            if (v > v1)      { v2 = v1; i2 = i1; v1 = v; i1 = e; }
            else if (v > v2) { v2 = v;  i2 = e; }
        }
        const float e2 = expf(v2 - v1);
        const float inv = 1.f / (1.f + e2);
        ids[n * 2] = i1;  ids[n * 2 + 1] = i2;
        probs[n * 2] = inv; probs[n * 2 + 1] = e2 * inv;
    }
}

// ---------------------------------------------------------------------------
// Exact sequential per-expert prefix count (reference cumsum semantics).
// ---------------------------------------------------------------------------
__global__ __launch_bounds__(256) void compute_pos(
    const int* __restrict__ ids, int* __restrict__ pos)
{
    __shared__ int hist[256][E_];
    const int t = threadIdx.x;
    const int per = NSLOT / 256;   // 128
    int cnt[E_];
#pragma unroll
    for (int e = 0; e < E_; e++) cnt[e] = 0;
    const int s0 = t * per;
    for (int i = 0; i < per; i++) cnt[ids[s0 + i]]++;
#pragma unroll
    for (int e = 0; e < E_; e++) hist[t][e] = cnt[e];
    __syncthreads();
    if (t < E_) {
        int run = 0;
        for (int i = 0; i < 256; i++) { const int c = hist[i][t]; hist[i][t] = run; run += c; }
    }
    __syncthreads();
    int run[E_];
#pragma unroll
    for (int e = 0; e < E_; e++) run[e] = hist[t][e];
    for (int i = 0; i < per; i++) { const int e = ids[s0 + i]; pos[s0 + i] = run[e]++; }
}

// ---------------------------------------------------------------------------
// Dispatch: copy kept tokens into per-expert buffers (bf16) + inverse map.
// ---------------------------------------------------------------------------
__global__ __launch_bounds__(256) void dispatch_k(
    const float* __restrict__ x, const int* __restrict__ ids,
    const int* __restrict__ pos, unsigned short* __restrict__ disp,
    int* __restrict__ slot_of)
{
    const int s = blockIdx.x;
    const int e = ids[s], p = pos[s];
    if (p >= CAP_) return;                      // dropped over capacity
    const int n = s >> 1;                       // K_ == 2
    const float4 v = *(const float4*)(x + (size_t)n * C_ + threadIdx.x * 4);
    ushort4 u;
    u.x = f2b(v.x); u.y = f2b(v.y); u.z = f2b(v.z); u.w = f2b(v.w);
    *(ushort4*)(disp + ((size_t)e * CAP_ + p) * C_ + threadIdx.x * 4) = u;
    if (threadIdx.x == 0) slot_of[e * CAP_ + p] = s;
}

// ---------------------------------------------------------------------------
extern "C" void kernel_launch(void* const* d_in, const int* in_sizes, int n_in,
                              void* d_out, int out_size, void* d_ws, size_t ws_size,
                              hipStream_t stream)
{
    const float* x   = (const float*)d_in[0];
    const float* rw1 = (const float*)d_in[1];
    const float* rb1 = (const float*)d_in[2];
    const float* rw2 = (const float*)d_in[3];
    const float* rb2 = (const float*)d_in[4];
    const float* ew1 = (const float*)d_in[5];
    const float* eb1 = (const float*)d_in[6];
    const float* ew2 = (const float*)d_in[7];
    const float* eb2 = (const float*)d_in[8];
    float* y = (float*)d_out;

    // ws layout (~403.3 MB), aliased by liveness:
    //  [0,128MiB)      h1 bf16 [16384][4096]           -> later hexp (low half)
    //  [128,256MiB)    hfix f32 [8192][4096] (exact rows) -> later hexp (high)
    //  [256,264MiB)    W16T fp16 (dead after approx GEMM)
    //  [256,352MiB)    Axc compact split-bf16 (after approx GEMM; dead after
    //                  exact GEMM)  -> later disp bf16 [256,320)
    //  [320,384MiB)    BTW expert weights (Axc/B2 dead by then)
    //  [352,376MiB)    B2 split-w (written after approx GEMM over dead x16)
    //  [352,384MiB)    x16 fp16 (dead after approx GEMM)
    //  [384MiB,...)    ids/probs/pos (128K each), iofn/list (64K), slot_of
    //                  (128K), count
    char* ws = (char*)d_ws;
    unsigned short* h1b    = (unsigned short*)ws;
    float*          hfix   = (float*)(ws + 134217728L);
    unsigned short* hexp   = (unsigned short*)ws;
    unsigned short* W16T   = (unsigned short*)(ws + 268435456L);
    unsigned short* Axc    = (unsigned short*)(ws + 268435456L);
    unsigned short* disp   = (unsigned short*)(ws + 268435456L);
    unsigned short* BTW    = (unsigned short*)(ws + 335544320L);
    unsigned short* B2     = (unsigned short*)(ws + 369098752L);
    unsigned short* x16    = (unsigned short*)(ws + 369098752L);
    int*            ids    = (int*)  (ws + 402653184L);
    float*          probs  = (float*)(ws + 402784256L);
    int*            pos    = (int*)  (ws + 402915328L);
    int*            iofn   = (int*)  (ws + 403046400L);
    int*            list   = (int*)  (ws + 403111936L);
    int*            slot_of= (int*)  (ws + 403177472L);
    int*            count  = (int*)  (ws + 403308544L);

    const size_t LDSB = 131072;   // 128 KiB: 2 dbuf x (A 32K + B 32K)

    hipMemsetAsync(count, 0, 128, stream);
    hipMemsetAsync(slot_of, 0xFF, (size_t)E_ * CAP_ * sizeof(int), stream);
    hipMemsetAsync(y, 0, (size_t)out_size * sizeof(float), stream);

    // 1a) fp16 operands for the approx router pass
    split_x16<<<NTOK, 256, 0, stream>>>(x, x16);
    {
        dim3 g(H_ / 32, C_ / 32, 1);
        transpose_cvt<true><<<g, 256, 0, stream>>>(rw1, W16T, C_, H_);
    }
    // 1b) Approx router GEMM1 (fp16, K=1024): h1b = relu(x16 @ rw1_16 + rb1), bf16 out
    {
        dim3 g(H_ / 256, NTOK / 256, 1);   // 16 x 64
        gemm256_8ph<1, unsigned short, true, 0><<<g, 512, LDSB, stream>>>(
            x16, W16T, rb1, h1b, C_, H_, C_ / 64, 0, 0, 0, 0,
            nullptr, nullptr, nullptr, nullptr);
    }
    // 2) Approx top-2 + softmax; flag near-ties (gap < MARGIN_)
    router_topk_approx<<<NTOK, 256, 0, stream>>>(h1b, rw2, rb2, ids, probs,
                                                 iofn, list, count);
    // 3a) Gather flagged tokens' 3-term split rows (x16/W16T now dead)
    gather_split<<<NTOK, 256, 0, stream>>>(x, list, count, Axc);
    {
        dim3 g(H_ / 32, C_ / 32, 1);
        split_w<<<g, 256, 0, stream>>>(rw1, B2);
    }
    // 3b) Exact router GEMM1 (split-bf16, ~fp32) on flagged rows only;
    //     compact f32 rows into hfix (blocks beyond count exit immediately)
    {
        dim3 g(H_ / 256, NTOK / 256, 1);
        gemm256_8ph<1, float, false, 1><<<g, 512, LDSB, stream>>>(
            Axc, B2, rb1, hfix, KR_, H_, KR_ / 64, 0, 0, 0, 0,
            count, nullptr, nullptr, nullptr);
    }
    // 3c) Recompute top-2 for flagged tokens from exact f32 rows
    router_topk_fix<<<NTOK, 256, 0, stream>>>(hfix, rw2, rb2, ids, probs, iofn);
    // 4) Exact sequential capacity positions
    compute_pos<<<1, 256, 0, stream>>>(ids, pos);
    // 5) Dispatch tokens to expert buffers (bf16) + slot_of inverse map
    dispatch_k<<<NSLOT, 256, 0, stream>>>(x, ids, pos, disp, slot_of);
    // 6a) Convert+transpose ew1 [8][1024][4096] -> BT1 bf16 [8][4096][1024]
    {
        dim3 g(H_ / 32, C_ / 32, E_);
        transpose_cvt<false><<<g, 256, 0, stream>>>(ew1, BTW, C_, H_);
    }
    // 6b) Expert GEMM1 (MFMA): hexp = relu(disp @ ew1 + eb1)   (h1b/hfix dead)
    {
        dim3 g(H_ / 256, CAP_ / 256, E_);
        gemm256_8ph<1, unsigned short, false, 0><<<g, 512, LDSB, stream>>>(
            disp, BTW, eb1, hexp, C_, H_, C_ / 64,
            (long)CAP_ * C_, (long)H_ * C_, (long)H_, (long)CAP_ * H_,
            nullptr, nullptr, nullptr, nullptr);
    }
    // 7a) Convert+transpose ew2 [8][4096][1024] -> BT2 bf16 [8][1024][4096]
    {
        dim3 g(C_ / 32, H_ / 32, E_);
        transpose_cvt<false><<<g, 256, 0, stream>>>(ew2, BTW, H_, C_);
    }
    // 7b) Expert GEMM2 + fused combine: y[(s>>1)] += probs[s] * (hexp@ew2+eb2)
    //     (<=2 commutative f32 adds per element from 0 -> deterministic)
    {
        dim3 g(C_ / 256, CAP_ / 256, E_);
        gemm256_8ph<0, float, false, 2><<<g, 512, LDSB, stream>>>(
            hexp, BTW, eb2, y, H_, C_, H_ / 64,
            (long)CAP_ * H_, (long)C_ * H_, (long)C_, 0,
            nullptr, slot_of, probs, y);
    }
}

// Round 14
// 1191.784 us; speedup vs baseline: 1.4177x; 1.4177x over previous
//
#include <hip/hip_runtime.h>
#include <cstdint>
#include <type_traits>

#define B_    8
#define T_    2048
#define C_    1024
#define E_    8
#define K_    2
#define CAP_  4096
#define H_    4096
#define NTOK  (B_ * T_)      // 16384
#define NSLOT (NTOK * K_)    // 32768
#define KR_   3072           // exact router split-GEMM K: [x_hi | x_lo | x_hi]

typedef __bf16 bf16x8 __attribute__((ext_vector_type(8)));
typedef float  f32x4  __attribute__((ext_vector_type(4)));

#define AS1 __attribute__((address_space(1)))
#define AS3 __attribute__((address_space(3)))

static __device__ __forceinline__ float b2f(unsigned short u) {
    union { float f; unsigned int i; } v; v.i = ((unsigned int)u) << 16; return v.f;
}
static __device__ __forceinline__ unsigned short f2b(float f) {
    unsigned int x = __float_as_uint(f);
    unsigned int r = (x + 0x7fffu + ((x >> 16) & 1u)) >> 16;   // RNE
    return (unsigned short)r;
}

template<int W> static __device__ __forceinline__ void vm_wait() {
    if constexpr (W == 4) asm volatile("s_waitcnt vmcnt(4)" ::: "memory");
    else if constexpr (W == 0) asm volatile("s_waitcnt vmcnt(0)" ::: "memory");
}

// ---------------------------------------------------------------------------
// 8-phase MFMA bf16 GEMM (round-9 proven schedule, 1202us — K-loop
// byte-identical): 256x256 tile, BK=64, 512 threads (8 waves 2Mx4N, wave
// tile 128x64), 2 LDS dbufs (128 KiB). Counted vmcnt(4) never 0 mid-loop;
// WAR/RAW ledger per round-9 derivation.
// EPI=0: normal store (f32 or bf16 via TC).
// EPI=3: fused router-logits epilogue — NO h1 store. h stays f32 in acc
//   (exactness preserved — round-13 lesson: any h rounding inflates logit
//   error). Per block: stage rw2[256 cols][8] slice in LDS (8KB), compute
//   p[8] per (row) from live acc, shfl_xor width-16 reduce over fr, write
//   per-wid LDS slices pl[4][256][8] (32KB, no atomics — each slot written
//   exactly once), then fixed-order sum of 4 slices -> plog[bx][row][8].
//   Fully deterministic.
// NOTE: 2 waves/SIMD structural (acc=128 regs); min-waves stays 2 (round-7:
// 4 -> acc spill -> 6x slower). Global atomic combine refuted (round-13:
// MfmaUtil 27%, +125us) — keep eo + gather combine.
// ---------------------------------------------------------------------------
template<int RELU, typename TC, int EPI>
__global__ __launch_bounds__(512, 2) void gemm256_8ph(
    const unsigned short* __restrict__ A, const unsigned short* __restrict__ BT,
    const float* __restrict__ bias, TC* __restrict__ Cout,
    int Kd, int Nld, int NT,
    long sA, long sB, long sBias, long sC,
    const float* __restrict__ rw2v, float* __restrict__ plogv)
{
    extern __shared__ char smem[];   // dbuf d: A at d*65536, B at d*65536+32768

    const int z = blockIdx.z;
    A    += (size_t)z * sA;
    BT   += (size_t)z * sB;
    bias += (size_t)z * sBias;
    if constexpr (EPI == 0) Cout += (size_t)z * sC;

    // XCD-aware swizzle (nwg % 8 == 0 for all our grids)
    const int gx = gridDim.x;
    const int nwg = gx * gridDim.y;
    int wg = blockIdx.y * gx + blockIdx.x;
    wg = (wg & 7) * (nwg >> 3) + (wg >> 3);
    const int bm = (wg / gx) * 256;
    const int bn = (wg % gx) * 256;

    const int tid  = threadIdx.x;
    const int lane = tid & 63;
    const int wid  = tid >> 6;
    const int wrow = (wid >> 2) * 128;   // wave M offset (2 waves in M)
    const int wcol = (wid & 3) * 64;     // wave N offset (4 waves in N)
    const int fr = lane & 15;            // fragment row/col within 16
    const int fq = lane >> 4;            // k-chunk selector (0..3)

    const size_t rbA = (size_t)Kd * 2;   // row stride in bytes (A and BT)
    const char* Ag = (const char*)A  + (size_t)bm * rbA;
    const char* Bg = (const char*)BT + (size_t)bn * rbA;

    f32x4 acc[8][4];
#pragma unroll
    for (int i = 0; i < 8; i++)
#pragma unroll
        for (int j = 0; j < 4; j++) acc[i][j] = (f32x4){0.f, 0.f, 0.f, 0.f};

    auto STAGE_A = [&](int kt) {
        char* d = smem + (size_t)(kt & 1) * 65536;
        const size_t kb = (size_t)kt * 128;
#pragma unroll
        for (int r = 0; r < 4; ++r) {
            const int o    = r * 8192 + tid * 16;
            const int row  = o >> 7;
            const int slot = (o >> 4) & 7;
            const int ss   = (slot ^ (row & 7)) << 4;
            __builtin_amdgcn_global_load_lds(
                (const AS1 void*)(Ag + (size_t)row * rbA + kb + ss),
                (AS3 void*)(d + r * 8192 + wid * 1024), 16, 0, 0);
        }
    };
    auto STAGE_B = [&](int kt) {
        char* d = smem + (size_t)(kt & 1) * 65536 + 32768;
        const size_t kb = (size_t)kt * 128;
#pragma unroll
        for (int r = 0; r < 4; ++r) {
            const int o    = r * 8192 + tid * 16;
            const int row  = o >> 7;
            const int slot = (o >> 4) & 7;
            const int ss   = (slot ^ (row & 7)) << 4;
            __builtin_amdgcn_global_load_lds(
                (const AS1 void*)(Bg + (size_t)row * rbA + kb + ss),
                (AS3 void*)(d + r * 8192 + wid * 1024), 16, 0, 0);
        }
    };

    auto LDA = [&](int kt, int mi, int kk) -> bf16x8 {
        const char* base = smem + (size_t)(kt & 1) * 65536;
        const int row  = wrow + mi * 16 + fr;
        const int slot = (kk * 4 + fq) ^ (row & 7);
        return *(const bf16x8*)(base + row * 128 + slot * 16);
    };
    auto LDB = [&](int kt, int ni, int kk) -> bf16x8 {
        const char* base = smem + (size_t)(kt & 1) * 65536 + 32768;
        const int row  = wcol + ni * 16 + fr;
        const int slot = (kk * 4 + fq) ^ (row & 7);
        return *(const bf16x8*)(base + row * 128 + slot * 16);
    };

    // ---- prologue
    STAGE_A(0); STAGE_B(0); STAGE_B(1);
    vm_wait<4>();
    __builtin_amdgcn_s_barrier();

    bf16x8 a[4], bb[4];
    for (int kt = 0; kt < NT; ++kt) {
        // ---------- ph0
#pragma unroll
        for (int i = 0; i < 4; ++i) a[i]  = LDA(kt, i, 0);
#pragma unroll
        for (int i = 0; i < 4; ++i) bb[i] = LDB(kt, i, 0);
        if (kt + 1 < NT) STAGE_A(kt + 1);
        __builtin_amdgcn_s_barrier();
        __builtin_amdgcn_s_setprio(1);
#pragma unroll
        for (int mi = 0; mi < 4; ++mi)
#pragma unroll
            for (int ni = 0; ni < 4; ++ni)
                acc[mi][ni] = __builtin_amdgcn_mfma_f32_16x16x32_bf16(
                    a[mi], bb[ni], acc[mi][ni], 0, 0, 0);
        __builtin_amdgcn_s_setprio(0);
        __builtin_amdgcn_s_barrier();
        // ---------- ph1
#pragma unroll
        for (int i = 0; i < 4; ++i) a[i] = LDA(kt, 4 + i, 0);
        __builtin_amdgcn_s_barrier();
        __builtin_amdgcn_s_setprio(1);
#pragma unroll
        for (int mi = 0; mi < 4; ++mi)
#pragma unroll
            for (int ni = 0; ni < 4; ++ni)
                acc[4 + mi][ni] = __builtin_amdgcn_mfma_f32_16x16x32_bf16(
                    a[mi], bb[ni], acc[4 + mi][ni], 0, 0, 0);
        __builtin_amdgcn_s_setprio(0);
        __builtin_amdgcn_s_barrier();
        // ---------- ph2
#pragma unroll
        for (int i = 0; i < 4; ++i) a[i]  = LDA(kt, i, 1);
#pragma unroll
        for (int i = 0; i < 4; ++i) bb[i] = LDB(kt, i, 1);
        __builtin_amdgcn_s_barrier();
        __builtin_amdgcn_s_setprio(1);
#pragma unroll
        for (int mi = 0; mi < 4; ++mi)
#pragma unroll
            for (int ni = 0; ni < 4; ++ni)
                acc[mi][ni] = __builtin_amdgcn_mfma_f32_16x16x32_bf16(
                    a[mi], bb[ni], acc[mi][ni], 0, 0, 0);
        __builtin_amdgcn_s_setprio(0);
        __builtin_amdgcn_s_barrier();
        // ---------- ph3
#pragma unroll
        for (int i = 0; i < 4; ++i) a[i] = LDA(kt, 4 + i, 1);
        if (kt + 2 < NT) STAGE_B(kt + 2);
        if (kt + 1 < NT) {
            if (kt + 2 < NT) vm_wait<4>();
            else             vm_wait<0>();
        }
        __builtin_amdgcn_s_barrier();
        __builtin_amdgcn_s_setprio(1);
#pragma unroll
        for (int mi = 0; mi < 4; ++mi)
#pragma unroll
            for (int ni = 0; ni < 4; ++ni)
                acc[4 + mi][ni] = __builtin_amdgcn_mfma_f32_16x16x32_bf16(
                    a[mi], bb[ni], acc[4 + mi][ni], 0, 0, 0);
        __builtin_amdgcn_s_setprio(0);
        __builtin_amdgcn_s_barrier();
    }

    // ---- epilogue. 16x16 C/D map: col=lane&15, row=fq*4+reg (round-6 proven)
    const float* bias_o = bias;
    asm volatile("" : "+s"(bias_o));

    if constexpr (EPI == 3) {
        // ---- fused router logits. After the K-loop's final barrier all LDS
        // reads are retired (each phase's ds_reads complete before its MFMAs
        // issue), so smem is reusable.
        float* rw2s = (float*)smem;            // [256][8] = 8KB
        float* pl   = (float*)(smem + 8192);   // [4][256][8] = 32KB
        *(float4*)(rw2s + tid * 4) =
            *(const float4*)(rw2v + (size_t)bn * 8 + tid * 4);
        __syncthreads();

        float bv[4];
#pragma unroll
        for (int ni = 0; ni < 4; ++ni)
            bv[ni] = bias_o[bn + wcol + ni * 16 + fr];

#pragma unroll
        for (int mi = 0; mi < 8; ++mi) {
#pragma unroll
            for (int rg = 0; rg < 4; ++rg) {
                float p[8];
#pragma unroll
                for (int e = 0; e < 8; ++e) p[e] = 0.f;
#pragma unroll
                for (int ni = 0; ni < 4; ++ni) {
                    const float h = fmaxf(acc[mi][ni][rg] + bv[ni], 0.f);
                    const float* w8 = rw2s + (wcol + ni * 16 + fr) * 8;
#pragma unroll
                    for (int e = 0; e < 8; ++e) p[e] = fmaf(h, w8[e], p[e]);
                }
#pragma unroll
                for (int e = 0; e < 8; ++e) {
                    p[e] += __shfl_xor(p[e], 1, 16);
                    p[e] += __shfl_xor(p[e], 2, 16);
                    p[e] += __shfl_xor(p[e], 4, 16);
                    p[e] += __shfl_xor(p[e], 8, 16);
                }
                if (fr == 0) {
                    const int row = wrow + mi * 16 + fq * 4 + rg;
                    float* dst = pl + ((wid & 3) * 256 + row) * 8;
#pragma unroll
                    for (int e = 0; e < 8; ++e) dst[e] = p[e];
                }
            }
        }
        __syncthreads();
        // fixed-order sum of the 4 wid slices -> plog[bx][bm+row][8]
        {
            const int idx = tid * 4;            // 2048 floats, idx&7 in {0,4}
            const float4 s0 = *(float4*)(pl + 0 * 2048 + idx);
            const float4 s1 = *(float4*)(pl + 1 * 2048 + idx);
            const float4 s2 = *(float4*)(pl + 2 * 2048 + idx);
            const float4 s3 = *(float4*)(pl + 3 * 2048 + idx);
            float4 r;
            r.x = ((s0.x + s1.x) + s2.x) + s3.x;
            r.y = ((s0.y + s1.y) + s2.y) + s3.y;
            r.z = ((s0.z + s1.z) + s2.z) + s3.z;
            r.w = ((s0.w + s1.w) + s2.w) + s3.w;
            const int row = idx >> 3, e0 = idx & 7;
            *(float4*)(plogv + ((size_t)(bn >> 8) * NTOK + bm + row) * 8 + e0) = r;
        }
    } else {
#pragma unroll
        for (int mi = 0; mi < 8; ++mi) {
#pragma unroll
            for (int ni = 0; ni < 4; ++ni) {
                const int c = bn + wcol + ni * 16 + fr;
                const float bv = bias_o[c];
#pragma unroll
                for (int rg = 0; rg < 4; ++rg) {
                    const int r = bm + wrow + mi * 16 + fq * 4 + rg;
                    float v = acc[mi][ni][rg] + bv;
                    if (RELU) v = fmaxf(v, 0.f);
                    if constexpr (std::is_same_v<TC, float>)
                        Cout[(size_t)r * Nld + c] = v;
                    else
                        Cout[(size_t)r * Nld + c] = f2b(v);
                }
            }
        }
    }
}

// ---------------------------------------------------------------------------
// Final router reduce: logits[n] = rb2 + sum_bx plog[bx][n][:] (fixed order,
// deterministic), then top-2 + softmax. One thread per token.
// ---------------------------------------------------------------------------
__global__ __launch_bounds__(256) void router_topk_final(
    const float* __restrict__ plog, const float* __restrict__ rb2,
    int* __restrict__ ids, float* __restrict__ probs)
{
    const int n = blockIdx.x * 256 + threadIdx.x;
    float l[E_];
#pragma unroll
    for (int e = 0; e < E_; ++e) l[e] = rb2[e];
#pragma unroll
    for (int bx = 0; bx < 16; ++bx) {
        const float4 a = *(const float4*)(plog + ((size_t)bx * NTOK + n) * 8);
        const float4 b = *(const float4*)(plog + ((size_t)bx * NTOK + n) * 8 + 4);
        l[0] += a.x; l[1] += a.y; l[2] += a.z; l[3] += a.w;
        l[4] += b.x; l[5] += b.y; l[6] += b.z; l[7] += b.w;
    }
    float v1 = -1e30f, v2 = -1e30f; int i1 = 0, i2 = 0;
#pragma unroll
    for (int e = 0; e < E_; ++e) {
        const float v = l[e];
        if (v > v1)      { v2 = v1; i2 = i1; v1 = v; i1 = e; }
        else if (v > v2) { v2 = v;  i2 = e; }
    }
    const float e2 = expf(v2 - v1);
    const float inv = 1.f / (1.f + e2);
    ids[n * 2] = i1;  ids[n * 2 + 1] = i2;
    probs[n * 2] = inv; probs[n * 2 + 1] = e2 * inv;
}

// ---------------------------------------------------------------------------
// Split x (fp32) -> A' bf16 [NTOK][3072] = [x_hi | x_lo | x_hi]
// ---------------------------------------------------------------------------
__global__ __launch_bounds__(256) void split_x(
    const float* __restrict__ x, unsigned short* __restrict__ A2)
{
    const int n = blockIdx.x;
    const int c = threadIdx.x * 4;
    const float4 v = *(const float4*)(x + (size_t)n * C_ + c);
    ushort4 hi, lo;
    hi.x = f2b(v.x); lo.x = f2b(v.x - b2f(hi.x));
    hi.y = f2b(v.y); lo.y = f2b(v.y - b2f(hi.y));
    hi.z = f2b(v.z); lo.z = f2b(v.z - b2f(hi.z));
    hi.w = f2b(v.w); lo.w = f2b(v.w - b2f(hi.w));
    unsigned short* row = A2 + (size_t)n * KR_;
    *(ushort4*)(row + c)            = hi;
    *(ushort4*)(row + C_ + c)       = lo;
    *(ushort4*)(row + 2 * C_ + c)   = hi;
}

// ---------------------------------------------------------------------------
// Split+transpose rw1 [C][H] fp32 -> B'^T bf16 [H][3072] = [w_hi | w_hi | w_lo]
// ---------------------------------------------------------------------------
__global__ __launch_bounds__(256) void split_w(
    const float* __restrict__ in, unsigned short* __restrict__ out)
{
    __shared__ float t[32][33];
    const int rb = blockIdx.y * 32;
    const int cb = blockIdx.x * 32;
    const int tr = threadIdx.x >> 3, tc = (threadIdx.x & 7) * 4;
    const float4 v = *(const float4*)(in + (size_t)(rb + tr) * H_ + cb + tc);
    t[tr][tc + 0] = v.x; t[tr][tc + 1] = v.y; t[tr][tc + 2] = v.z; t[tr][tc + 3] = v.w;
    __syncthreads();
    ushort4 hi, lo;
    float f;
    f = t[tc + 0][tr]; hi.x = f2b(f); lo.x = f2b(f - b2f(hi.x));
    f = t[tc + 1][tr]; hi.y = f2b(f); lo.y = f2b(f - b2f(hi.y));
    f = t[tc + 2][tr]; hi.z = f2b(f); lo.z = f2b(f - b2f(hi.z));
    f = t[tc + 3][tr]; hi.w = f2b(f); lo.w = f2b(f - b2f(hi.w));
    unsigned short* row = out + (size_t)(cb + tr) * KR_;
    *(ushort4*)(row + rb + tc)           = hi;
    *(ushort4*)(row + C_ + rb + tc)      = hi;
    *(ushort4*)(row + 2 * C_ + rb + tc)  = lo;
}

// ---------------------------------------------------------------------------
// Tiled transpose + fp32->bf16 convert: in [z][R][Ncols] f32 -> out [z][Ncols][R] bf16
// ---------------------------------------------------------------------------
__global__ __launch_bounds__(256) void transpose_cvt(
    const float* __restrict__ in, unsigned short* __restrict__ out, int R, int Ncols)
{
    __shared__ float t[32][33];
    const size_t zoff = (size_t)blockIdx.z * R * Ncols;
    in  += zoff;
    out += zoff;
    const int rb = blockIdx.y * 32, cb = blockIdx.x * 32;
    const int tr = threadIdx.x >> 3, tc = (threadIdx.x & 7) * 4;
    const float4 v = *(const float4*)(in + (size_t)(rb + tr) * Ncols + cb + tc);
    t[tr][tc + 0] = v.x; t[tr][tc + 1] = v.y; t[tr][tc + 2] = v.z; t[tr][tc + 3] = v.w;
    __syncthreads();
    ushort4 u;
    u.x = f2b(t[tc + 0][tr]); u.y = f2b(t[tc + 1][tr]);
    u.z = f2b(t[tc + 2][tr]); u.w = f2b(t[tc + 3][tr]);
    *(ushort4*)(out + (size_t)(cb + tr) * R + rb + tc) = u;
}

// ---------------------------------------------------------------------------
// Exact sequential per-expert prefix count (reference cumsum semantics).
// ---------------------------------------------------------------------------
__global__ __launch_bounds__(256) void compute_pos(
    const int* __restrict__ ids, int* __restrict__ pos)
{
    __shared__ int hist[256][E_];
    const int t = threadIdx.x;
    const int per = NSLOT / 256;   // 128
    int cnt[E_];
#pragma unroll
    for (int e = 0; e < E_; e++) cnt[e] = 0;
    const int s0 = t * per;
    for (int i = 0; i < per; i++) cnt[ids[s0 + i]]++;
#pragma unroll
    for (int e = 0; e < E_; e++) hist[t][e] = cnt[e];
    __syncthreads();
    if (t < E_) {
        int run = 0;
        for (int i = 0; i < 256; i++) { const int c = hist[i][t]; hist[i][t] = run; run += c; }
    }
    __syncthreads();
    int run[E_];
#pragma unroll
    for (int e = 0; e < E_; e++) run[e] = hist[t][e];
    for (int i = 0; i < per; i++) { const int e = ids[s0 + i]; pos[s0 + i] = run[e]++; }
}

// ---------------------------------------------------------------------------
// Dispatch: copy kept tokens into per-expert buffers (bf16).
// ---------------------------------------------------------------------------
__global__ __launch_bounds__(256) void dispatch_k(
    const float* __restrict__ x, const int* __restrict__ ids,
    const int* __restrict__ pos, unsigned short* __restrict__ disp)
{
    const int s = blockIdx.x;
    const int e = ids[s], p = pos[s];
    if (p >= CAP_) return;                      // dropped over capacity
    const int n = s >> 1;                       // K_ == 2
    const float4 v = *(const float4*)(x + (size_t)n * C_ + threadIdx.x * 4);
    ushort4 u;
    u.x = f2b(v.x); u.y = f2b(v.y); u.z = f2b(v.z); u.w = f2b(v.w);
    *(ushort4*)(disp + ((size_t)e * CAP_ + p) * C_ + threadIdx.x * 4) = u;
}

// ---------------------------------------------------------------------------
// Combine (gather, race-free): y[n] = sum_k probs * eo[id_k, pos_k]
// ---------------------------------------------------------------------------
__global__ __launch_bounds__(256) void combine_k(
    const unsigned short* __restrict__ eo, const int* __restrict__ ids,
    const int* __restrict__ pos, const float* __restrict__ probs,
    float* __restrict__ y)
{
    const int n = blockIdx.x;
    const int c = threadIdx.x * 4;
    float r0 = 0.f, r1 = 0.f, r2 = 0.f, r3 = 0.f;
#pragma unroll
    for (int k = 0; k < K_; k++) {
        const int p = pos[2 * n + k];
        if (p >= CAP_) continue;
        const int e = ids[2 * n + k];
        const float w = probs[2 * n + k];
        const ushort4 u = *(const ushort4*)(eo + ((size_t)e * CAP_ + p) * C_ + c);
        r0 = fmaf(w, b2f(u.x), r0); r1 = fmaf(w, b2f(u.y), r1);
        r2 = fmaf(w, b2f(u.z), r2); r3 = fmaf(w, b2f(u.w), r3);
    }
    *(float4*)(y + (size_t)n * C_ + c) = make_float4(r0, r1, r2, r3);
}

// ---------------------------------------------------------------------------
extern "C" void kernel_launch(void* const* d_in, const int* in_sizes, int n_in,
                              void* d_out, int out_size, void* d_ws, size_t ws_size,
                              hipStream_t stream)
{
    const float* x   = (const float*)d_in[0];
    const float* rw1 = (const float*)d_in[1];
    const float* rb1 = (const float*)d_in[2];
    const float* rw2 = (const float*)d_in[3];
    const float* rb2 = (const float*)d_in[4];
    const float* ew1 = (const float*)d_in[5];
    const float* eb1 = (const float*)d_in[6];
    const float* ew2 = (const float*)d_in[7];
    const float* eb2 = (const float*)d_in[8];
    float* y = (float*)d_out;

    // ws layout (<= 384.4 MiB), aliased by liveness:
    //  [0,256MiB)      hexp bf16 [8][4096][4096] (expert GEMM1 out; no h1!)
    //  [256,352MiB)    A2 split-x bf16 [16384][3072] (router) -> later
    //                  disp bf16 [256,320) -> later eo bf16 [256,320)
    //  [320,384MiB)    BTW expert weights (written at 5a, A2/B2/plog dead)
    //  [352,376MiB)    B2 split-w bf16 [4096][3072] (router)
    //  [376,384MiB)    plog f32 [16][16384][8] (router partial logits)
    //  [384MiB,...)    ids / probs / pos (128KiB each)
    char* ws = (char*)d_ws;
    unsigned short* hexp  = (unsigned short*)ws;
    unsigned short* A2    = (unsigned short*)(ws + 268435456L);
    unsigned short* disp  = (unsigned short*)(ws + 268435456L);
    unsigned short* eo    = (unsigned short*)(ws + 268435456L);
    unsigned short* BTW   = (unsigned short*)(ws + 335544320L);
    unsigned short* B2    = (unsigned short*)(ws + 369098752L);
    float*          plog  = (float*)(ws + 394264576L);
    int*            ids   = (int*)  (ws + 402653184L);
    float*          probs = (float*)(ws + 402784256L);
    int*            pos   = (int*)  (ws + 402915328L);

    const size_t LDSB = 131072;   // 128 KiB: 2 dbuf x (A 32K + B 32K)

    // 1a) Build split operands for router GEMM1
    split_x<<<NTOK, 256, 0, stream>>>(x, A2);
    {
        dim3 g(H_ / 32, C_ / 32, 1);
        split_w<<<g, 256, 0, stream>>>(rw1, B2);
    }
    // 1b) Router GEMM1 (split-bf16, ~fp32 exact) + FUSED logits epilogue:
    //     plog[bx][n][8] partial logits; h1 never touches HBM.
    {
        dim3 g(H_ / 256, NTOK / 256, 1);   // 16 x 64
        gemm256_8ph<1, float, 3><<<g, 512, LDSB, stream>>>(
            A2, B2, rb1, (float*)nullptr, KR_, H_, KR_ / 64, 0, 0, 0, 0,
            rw2, plog);
    }
    // 2) Deterministic final reduce + top-2 + softmax
    router_topk_final<<<NTOK / 256, 256, 0, stream>>>(plog, rb2, ids, probs);
    // 3) Exact sequential capacity positions
    compute_pos<<<1, 256, 0, stream>>>(ids, pos);
    // 4) Dispatch tokens to expert buffers (bf16) — overwrites A2 (dead)
    dispatch_k<<<NSLOT, 256, 0, stream>>>(x, ids, pos, disp);
    // 5a) Convert+transpose ew1 [8][1024][4096] -> BT1 bf16 [8][4096][1024]
    {
        dim3 g(H_ / 32, C_ / 32, E_);
        transpose_cvt<<<g, 256, 0, stream>>>(ew1, BTW, C_, H_);
    }
    // 5b) Expert GEMM1 (MFMA): hexp = relu(disp @ ew1 + eb1)
    {
        dim3 g(H_ / 256, CAP_ / 256, E_);   // 16 x 16 x 8
        gemm256_8ph<1, unsigned short, 0><<<g, 512, LDSB, stream>>>(
            disp, BTW, eb1, hexp, C_, H_, C_ / 64,
            (long)CAP_ * C_, (long)H_ * C_, (long)H_, (long)CAP_ * H_,
            nullptr, nullptr);
    }
    // 6a) Convert+transpose ew2 [8][4096][1024] -> BT2 bf16 [8][1024][4096]
    {
        dim3 g(C_ / 32, H_ / 32, E_);
        transpose_cvt<<<g, 256, 0, stream>>>(ew2, BTW, H_, C_);
    }
    // 6b) Expert GEMM2 (MFMA): eo = hexp @ ew2 + eb2   (bf16 out; disp dead)
    {
        dim3 g(C_ / 256, CAP_ / 256, E_);   // 4 x 16 x 8
        gemm256_8ph<0, unsigned short, 0><<<g, 512, LDSB, stream>>>(
            hexp, BTW, eb2, eo, H_, C_, H_ / 64,
            (long)CAP_ * H_, (long)C_ * H_, (long)C_, (long)CAP_ * C_,
            nullptr, nullptr);
    }
    // 7) Combine: gather expert outputs, weight, sum (race-free, writes all y)
    combine_k<<<NTOK, 256, 0, stream>>>(eo, ids, pos, probs, y);
}

// Round 15
// 1064.020 us; speedup vs baseline: 1.5879x; 1.1201x over previous
//
#include <hip/hip_runtime.h>
#include <cstdint>
#include <type_traits>

#define B_    8
#define T_    2048
#define C_    1024
#define E_    8
#define K_    2
#define CAP_  4096
#define H_    4096
#define NTOK  (B_ * T_)      // 16384
#define NSLOT (NTOK * K_)    // 32768
#define KR_   3072           // exact router split-GEMM K: [x_hi | x_lo | x_hi]

typedef __bf16 bf16x8 __attribute__((ext_vector_type(8)));
typedef float  f32x4  __attribute__((ext_vector_type(4)));

#define AS1 __attribute__((address_space(1)))
#define AS3 __attribute__((address_space(3)))

static __device__ __forceinline__ float b2f(unsigned short u) {
    union { float f; unsigned int i; } v; v.i = ((unsigned int)u) << 16; return v.f;
}
static __device__ __forceinline__ unsigned short f2b(float f) {
    unsigned int x = __float_as_uint(f);
    unsigned int r = (x + 0x7fffu + ((x >> 16) & 1u)) >> 16;   // RNE
    return (unsigned short)r;
}

template<int W> static __device__ __forceinline__ void vm_wait() {
    if constexpr (W == 4) asm volatile("s_waitcnt vmcnt(4)" ::: "memory");
    else if constexpr (W == 0) asm volatile("s_waitcnt vmcnt(0)" ::: "memory");
}

// ---------------------------------------------------------------------------
// 8-phase MFMA bf16 GEMM (round-9 proven schedule — K-loop byte-identical):
// 256x256 tile, BK=64, 512 threads (8 waves 2Mx4N, wave tile 128x64), 2 LDS
// dbufs (128 KiB). Counted vmcnt(4) never 0 mid-loop; round-9 hazard ledger.
// EPI=0: normal store (f32 or bf16 via TC).
// EPI=3: fused router-logits epilogue v2 — NO h1 store; h stays f32 in acc.
//   Round-14 lesson: 4-level shfl tree + LDS-staged rw2 = ~2k LDS ops/lane
//   (+150us, 4.8e7 bank conflicts). v2: rw2 slice in REGISTERS (32 f32),
//   2 shfl levels only, then one 128KiB LDS buffer pass:
//     pb[rowhalf2][colwave4][row128][frq4][e8]  (= exactly the dead dbuf)
//   each slot written exactly once (no atomics); final fixed-order sum over
//   (colwave, frq) -> plog[bx][n][8]. Fully deterministic.
// NOTE: 2 waves/SIMD structural (acc=128 regs); min-waves stays 2 (round-7:
// 4 -> acc spill -> 6x slower). Global atomic combine refuted (round-13).
// ---------------------------------------------------------------------------
template<int RELU, typename TC, int EPI>
__global__ __launch_bounds__(512, 2) void gemm256_8ph(
    const unsigned short* __restrict__ A, const unsigned short* __restrict__ BT,
    const float* __restrict__ bias, TC* __restrict__ Cout,
    int Kd, int Nld, int NT,
    long sA, long sB, long sBias, long sC,
    const float* __restrict__ rw2v, float* __restrict__ plogv)
{
    extern __shared__ char smem[];   // dbuf d: A at d*65536, B at d*65536+32768

    const int z = blockIdx.z;
    A    += (size_t)z * sA;
    BT   += (size_t)z * sB;
    bias += (size_t)z * sBias;
    if constexpr (EPI == 0) Cout += (size_t)z * sC;

    // XCD-aware swizzle (nwg % 8 == 0 for all our grids)
    const int gx = gridDim.x;
    const int nwg = gx * gridDim.y;
    int wg = blockIdx.y * gx + blockIdx.x;
    wg = (wg & 7) * (nwg >> 3) + (wg >> 3);
    const int bm = (wg / gx) * 256;
    const int bn = (wg % gx) * 256;

    const int tid  = threadIdx.x;
    const int lane = tid & 63;
    const int wid  = tid >> 6;
    const int wrow = (wid >> 2) * 128;   // wave M offset (2 waves in M)
    const int wcol = (wid & 3) * 64;     // wave N offset (4 waves in N)
    const int fr = lane & 15;            // fragment row/col within 16
    const int fq = lane >> 4;            // k-chunk selector (0..3)

    const size_t rbA = (size_t)Kd * 2;   // row stride in bytes (A and BT)
    const char* Ag = (const char*)A  + (size_t)bm * rbA;
    const char* Bg = (const char*)BT + (size_t)bn * rbA;

    f32x4 acc[8][4];
#pragma unroll
    for (int i = 0; i < 8; i++)
#pragma unroll
        for (int j = 0; j < 4; j++) acc[i][j] = (f32x4){0.f, 0.f, 0.f, 0.f};

    auto STAGE_A = [&](int kt) {
        char* d = smem + (size_t)(kt & 1) * 65536;
        const size_t kb = (size_t)kt * 128;
#pragma unroll
        for (int r = 0; r < 4; ++r) {
            const int o    = r * 8192 + tid * 16;
            const int row  = o >> 7;
            const int slot = (o >> 4) & 7;
            const int ss   = (slot ^ (row & 7)) << 4;
            __builtin_amdgcn_global_load_lds(
                (const AS1 void*)(Ag + (size_t)row * rbA + kb + ss),
                (AS3 void*)(d + r * 8192 + wid * 1024), 16, 0, 0);
        }
    };
    auto STAGE_B = [&](int kt) {
        char* d = smem + (size_t)(kt & 1) * 65536 + 32768;
        const size_t kb = (size_t)kt * 128;
#pragma unroll
        for (int r = 0; r < 4; ++r) {
            const int o    = r * 8192 + tid * 16;
            const int row  = o >> 7;
            const int slot = (o >> 4) & 7;
            const int ss   = (slot ^ (row & 7)) << 4;
            __builtin_amdgcn_global_load_lds(
                (const AS1 void*)(Bg + (size_t)row * rbA + kb + ss),
                (AS3 void*)(d + r * 8192 + wid * 1024), 16, 0, 0);
        }
    };

    auto LDA = [&](int kt, int mi, int kk) -> bf16x8 {
        const char* base = smem + (size_t)(kt & 1) * 65536;
        const int row  = wrow + mi * 16 + fr;
        const int slot = (kk * 4 + fq) ^ (row & 7);
        return *(const bf16x8*)(base + row * 128 + slot * 16);
    };
    auto LDB = [&](int kt, int ni, int kk) -> bf16x8 {
        const char* base = smem + (size_t)(kt & 1) * 65536 + 32768;
        const int row  = wcol + ni * 16 + fr;
        const int slot = (kk * 4 + fq) ^ (row & 7);
        return *(const bf16x8*)(base + row * 128 + slot * 16);
    };

    // ---- prologue
    STAGE_A(0); STAGE_B(0); STAGE_B(1);
    vm_wait<4>();
    __builtin_amdgcn_s_barrier();

    bf16x8 a[4], bb[4];
    for (int kt = 0; kt < NT; ++kt) {
        // ---------- ph0
#pragma unroll
        for (int i = 0; i < 4; ++i) a[i]  = LDA(kt, i, 0);
#pragma unroll
        for (int i = 0; i < 4; ++i) bb[i] = LDB(kt, i, 0);
        if (kt + 1 < NT) STAGE_A(kt + 1);
        __builtin_amdgcn_s_barrier();
        __builtin_amdgcn_s_setprio(1);
#pragma unroll
        for (int mi = 0; mi < 4; ++mi)
#pragma unroll
            for (int ni = 0; ni < 4; ++ni)
                acc[mi][ni] = __builtin_amdgcn_mfma_f32_16x16x32_bf16(
                    a[mi], bb[ni], acc[mi][ni], 0, 0, 0);
        __builtin_amdgcn_s_setprio(0);
        __builtin_amdgcn_s_barrier();
        // ---------- ph1
#pragma unroll
        for (int i = 0; i < 4; ++i) a[i] = LDA(kt, 4 + i, 0);
        __builtin_amdgcn_s_barrier();
        __builtin_amdgcn_s_setprio(1);
#pragma unroll
        for (int mi = 0; mi < 4; ++mi)
#pragma unroll
            for (int ni = 0; ni < 4; ++ni)
                acc[4 + mi][ni] = __builtin_amdgcn_mfma_f32_16x16x32_bf16(
                    a[mi], bb[ni], acc[4 + mi][ni], 0, 0, 0);
        __builtin_amdgcn_s_setprio(0);
        __builtin_amdgcn_s_barrier();
        // ---------- ph2
#pragma unroll
        for (int i = 0; i < 4; ++i) a[i]  = LDA(kt, i, 1);
#pragma unroll
        for (int i = 0; i < 4; ++i) bb[i] = LDB(kt, i, 1);
        __builtin_amdgcn_s_barrier();
        __builtin_amdgcn_s_setprio(1);
#pragma unroll
        for (int mi = 0; mi < 4; ++mi)
#pragma unroll
            for (int ni = 0; ni < 4; ++ni)
                acc[mi][ni] = __builtin_amdgcn_mfma_f32_16x16x32_bf16(
                    a[mi], bb[ni], acc[mi][ni], 0, 0, 0);
        __builtin_amdgcn_s_setprio(0);
        __builtin_amdgcn_s_barrier();
        // ---------- ph3
#pragma unroll
        for (int i = 0; i < 4; ++i) a[i] = LDA(kt, 4 + i, 1);
        if (kt + 2 < NT) STAGE_B(kt + 2);
        if (kt + 1 < NT) {
            if (kt + 2 < NT) vm_wait<4>();
            else             vm_wait<0>();
        }
        __builtin_amdgcn_s_barrier();
        __builtin_amdgcn_s_setprio(1);
#pragma unroll
        for (int mi = 0; mi < 4; ++mi)
#pragma unroll
            for (int ni = 0; ni < 4; ++ni)
                acc[4 + mi][ni] = __builtin_amdgcn_mfma_f32_16x16x32_bf16(
                    a[mi], bb[ni], acc[4 + mi][ni], 0, 0, 0);
        __builtin_amdgcn_s_setprio(0);
        __builtin_amdgcn_s_barrier();
    }

    // ---- epilogue. 16x16 C/D map: col=lane&15, row=fq*4+reg (round-6 proven)
    const float* bias_o = bias;
    asm volatile("" : "+s"(bias_o));

    if constexpr (EPI == 3) {
        // After the final barrier all LDS reads are retired and no
        // global_load_lds is outstanding -> smem fully reusable (proven r14).
        // rw2 slice in REGISTERS (no LDS reads at all):
        float w2r[4][8];
#pragma unroll
        for (int ni = 0; ni < 4; ++ni) {
            const float* src = rw2v + (size_t)(bn + wcol + ni * 16 + fr) * 8;
            *(float4*)(w2r[ni])     = *(const float4*)(src);
            *(float4*)(w2r[ni] + 4) = *(const float4*)(src + 4);
        }
        float bv[4];
#pragma unroll
        for (int ni = 0; ni < 4; ++ni)
            bv[ni] = bias_o[bn + wcol + ni * 16 + fr];

        // pb[rowhalf2][colwave4][row128][frq4][e8] = 128 KiB exactly
        float* pb = (float*)smem;
        const int rowhalf = wid >> 2, colwave = wid & 3;
        const int frq = fr >> 2;

#pragma unroll
        for (int mi = 0; mi < 8; ++mi) {
#pragma unroll
            for (int rg = 0; rg < 4; ++rg) {
                float p[8];
#pragma unroll
                for (int e = 0; e < 8; ++e) p[e] = 0.f;
#pragma unroll
                for (int ni = 0; ni < 4; ++ni) {
                    const float h = fmaxf(acc[mi][ni][rg] + bv[ni], 0.f);
#pragma unroll
                    for (int e = 0; e < 8; ++e) p[e] = fmaf(h, w2r[ni][e], p[e]);
                }
                // 2 shfl levels: sum over fr groups of 4 (lane^1, lane^2
                // stay within the same fq quarter since fr = lane&15)
#pragma unroll
                for (int e = 0; e < 8; ++e) {
                    p[e] += __shfl_xor(p[e], 1);
                    p[e] += __shfl_xor(p[e], 2);
                }
                if ((fr & 3) == 0) {
                    const int row = mi * 16 + fq * 4 + rg;   // 0..127 in-wave
                    float* dst = pb +
                        ((((size_t)rowhalf * 4 + colwave) * 128 + row) * 4 + frq) * 8;
                    *(float4*)(dst)     = make_float4(p[0], p[1], p[2], p[3]);
                    *(float4*)(dst + 4) = make_float4(p[4], p[5], p[6], p[7]);
                }
            }
        }
        __syncthreads();
        // fixed-order deterministic sum over (colwave, frq):
        // thread t -> row r = t>>1 (0..255), expert-half eh = t&1
        {
            const int r  = tid >> 1;
            const int eh = (tid & 1) * 4;
            const int rowhalf2 = r >> 7, rl = r & 127;
            float4 s = make_float4(0.f, 0.f, 0.f, 0.f);
#pragma unroll
            for (int cw = 0; cw < 4; ++cw)
#pragma unroll
                for (int q = 0; q < 4; ++q) {
                    const float4 v = *(const float4*)(pb +
                        ((((size_t)rowhalf2 * 4 + cw) * 128 + rl) * 4 + q) * 8 + eh);
                    s.x += v.x; s.y += v.y; s.z += v.z; s.w += v.w;
                }
            *(float4*)(plogv + ((size_t)(bn >> 8) * NTOK + bm + r) * 8 + eh) = s;
        }
    } else {
#pragma unroll
        for (int mi = 0; mi < 8; ++mi) {
#pragma unroll
            for (int ni = 0; ni < 4; ++ni) {
                const int c = bn + wcol + ni * 16 + fr;
                const float bv = bias_o[c];
#pragma unroll
                for (int rg = 0; rg < 4; ++rg) {
                    const int r = bm + wrow + mi * 16 + fq * 4 + rg;
                    float v = acc[mi][ni][rg] + bv;
                    if (RELU) v = fmaxf(v, 0.f);
                    if constexpr (std::is_same_v<TC, float>)
                        Cout[(size_t)r * Nld + c] = v;
                    else
                        Cout[(size_t)r * Nld + c] = f2b(v);
                }
            }
        }
    }
}

// ---------------------------------------------------------------------------
// Final router reduce: logits[n] = rb2 + sum_bx plog[bx][n][:] (fixed order,
// deterministic), then top-2 + softmax. One thread per token.
// ---------------------------------------------------------------------------
__global__ __launch_bounds__(256) void router_topk_final(
    const float* __restrict__ plog, const float* __restrict__ rb2,
    int* __restrict__ ids, float* __restrict__ probs)
{
    const int n = blockIdx.x * 256 + threadIdx.x;
    float l[E_];
#pragma unroll
    for (int e = 0; e < E_; ++e) l[e] = rb2[e];
#pragma unroll
    for (int bx = 0; bx < 16; ++bx) {
        const float4 a = *(const float4*)(plog + ((size_t)bx * NTOK + n) * 8);
        const float4 b = *(const float4*)(plog + ((size_t)bx * NTOK + n) * 8 + 4);
        l[0] += a.x; l[1] += a.y; l[2] += a.z; l[3] += a.w;
        l[4] += b.x; l[5] += b.y; l[6] += b.z; l[7] += b.w;
    }
    float v1 = -1e30f, v2 = -1e30f; int i1 = 0, i2 = 0;
#pragma unroll
    for (int e = 0; e < E_; ++e) {
        const float v = l[e];
        if (v > v1)      { v2 = v1; i2 = i1; v1 = v; i1 = e; }
        else if (v > v2) { v2 = v;  i2 = e; }
    }
    const float e2 = expf(v2 - v1);
    const float inv = 1.f / (1.f + e2);
    ids[n * 2] = i1;  ids[n * 2 + 1] = i2;
    probs[n * 2] = inv; probs[n * 2 + 1] = e2 * inv;
}

// ---------------------------------------------------------------------------
// Split x (fp32) -> A' bf16 [NTOK][3072] = [x_hi | x_lo | x_hi]
// ---------------------------------------------------------------------------
__global__ __launch_bounds__(256) void split_x(
    const float* __restrict__ x, unsigned short* __restrict__ A2)
{
    const int n = blockIdx.x;
    const int c = threadIdx.x * 4;
    const float4 v = *(const float4*)(x + (size_t)n * C_ + c);
    ushort4 hi, lo;
    hi.x = f2b(v.x); lo.x = f2b(v.x - b2f(hi.x));
    hi.y = f2b(v.y); lo.y = f2b(v.y - b2f(hi.y));
    hi.z = f2b(v.z); lo.z = f2b(v.z - b2f(hi.z));
    hi.w = f2b(v.w); lo.w = f2b(v.w - b2f(hi.w));
    unsigned short* row = A2 + (size_t)n * KR_;
    *(ushort4*)(row + c)            = hi;
    *(ushort4*)(row + C_ + c)       = lo;
    *(ushort4*)(row + 2 * C_ + c)   = hi;
}

// ---------------------------------------------------------------------------
// Split+transpose rw1 [C][H] fp32 -> B'^T bf16 [H][3072] = [w_hi | w_hi | w_lo]
// ---------------------------------------------------------------------------
__global__ __launch_bounds__(256) void split_w(
    const float* __restrict__ in, unsigned short* __restrict__ out)
{
    __shared__ float t[32][33];
    const int rb = blockIdx.y * 32;
    const int cb = blockIdx.x * 32;
    const int tr = threadIdx.x >> 3, tc = (threadIdx.x & 7) * 4;
    const float4 v = *(const float4*)(in + (size_t)(rb + tr) * H_ + cb + tc);
    t[tr][tc + 0] = v.x; t[tr][tc + 1] = v.y; t[tr][tc + 2] = v.z; t[tr][tc + 3] = v.w;
    __syncthreads();
    ushort4 hi, lo;
    float f;
    f = t[tc + 0][tr]; hi.x = f2b(f); lo.x = f2b(f - b2f(hi.x));
    f = t[tc + 1][tr]; hi.y = f2b(f); lo.y = f2b(f - b2f(hi.y));
    f = t[tc + 2][tr]; hi.z = f2b(f); lo.z = f2b(f - b2f(hi.z));
    f = t[tc + 3][tr]; hi.w = f2b(f); lo.w = f2b(f - b2f(hi.w));
    unsigned short* row = out + (size_t)(cb + tr) * KR_;
    *(ushort4*)(row + rb + tc)           = hi;
    *(ushort4*)(row + C_ + rb + tc)      = hi;
    *(ushort4*)(row + 2 * C_ + rb + tc)  = lo;
}

// ---------------------------------------------------------------------------
// Tiled transpose + fp32->bf16 convert: in [z][R][Ncols] f32 -> out [z][Ncols][R] bf16
// ---------------------------------------------------------------------------
__global__ __launch_bounds__(256) void transpose_cvt(
    const float* __restrict__ in, unsigned short* __restrict__ out, int R, int Ncols)
{
    __shared__ float t[32][33];
    const size_t zoff = (size_t)blockIdx.z * R * Ncols;
    in  += zoff;
    out += zoff;
    const int rb = blockIdx.y * 32, cb = blockIdx.x * 32;
    const int tr = threadIdx.x >> 3, tc = (threadIdx.x & 7) * 4;
    const float4 v = *(const float4*)(in + (size_t)(rb + tr) * Ncols + cb + tc);
    t[tr][tc + 0] = v.x; t[tr][tc + 1] = v.y; t[tr][tc + 2] = v.z; t[tr][tc + 3] = v.w;
    __syncthreads();
    ushort4 u;
    u.x = f2b(t[tc + 0][tr]); u.y = f2b(t[tc + 1][tr]);
    u.z = f2b(t[tc + 2][tr]); u.w = f2b(t[tc + 3][tr]);
    *(ushort4*)(out + (size_t)(cb + tr) * R + rb + tc) = u;
}

// ---------------------------------------------------------------------------
// Exact sequential per-expert prefix count (reference cumsum semantics).
// ---------------------------------------------------------------------------
__global__ __launch_bounds__(256) void compute_pos(
    const int* __restrict__ ids, int* __restrict__ pos)
{
    __shared__ int hist[256][E_];
    const int t = threadIdx.x;
    const int per = NSLOT / 256;   // 128
    int cnt[E_];
#pragma unroll
    for (int e = 0; e < E_; e++) cnt[e] = 0;
    const int s0 = t * per;
    for (int i = 0; i < per; i++) cnt[ids[s0 + i]]++;
#pragma unroll
    for (int e = 0; e < E_; e++) hist[t][e] = cnt[e];
    __syncthreads();
    if (t < E_) {
        int run = 0;
        for (int i = 0; i < 256; i++) { const int c = hist[i][t]; hist[i][t] = run; run += c; }
    }
    __syncthreads();
    int run[E_];
#pragma unroll
    for (int e = 0; e < E_; e++) run[e] = hist[t][e];
    for (int i = 0; i < per; i++) { const int e = ids[s0 + i]; pos[s0 + i] = run[e]++; }
}

// ---------------------------------------------------------------------------
// Dispatch: copy kept tokens into per-expert buffers (bf16).
// ---------------------------------------------------------------------------
__global__ __launch_bounds__(256) void dispatch_k(
    const float* __restrict__ x, const int* __restrict__ ids,
    const int* __restrict__ pos, unsigned short* __restrict__ disp)
{
    const int s = blockIdx.x;
    const int e = ids[s], p = pos[s];
    if (p >= CAP_) return;                      // dropped over capacity
    const int n = s >> 1;                       // K_ == 2
    const float4 v = *(const float4*)(x + (size_t)n * C_ + threadIdx.x * 4);
    ushort4 u;
    u.x = f2b(v.x); u.y = f2b(v.y); u.z = f2b(v.z); u.w = f2b(v.w);
    *(ushort4*)(disp + ((size_t)e * CAP_ + p) * C_ + threadIdx.x * 4) = u;
}

// ---------------------------------------------------------------------------
// Combine (gather, race-free): y[n] = sum_k probs * eo[id_k, pos_k]
// ---------------------------------------------------------------------------
__global__ __launch_bounds__(256) void combine_k(
    const unsigned short* __restrict__ eo, const int* __restrict__ ids,
    const int* __restrict__ pos, const float* __restrict__ probs,
    float* __restrict__ y)
{
    const int n = blockIdx.x;
    const int c = threadIdx.x * 4;
    float r0 = 0.f, r1 = 0.f, r2 = 0.f, r3 = 0.f;
#pragma unroll
    for (int k = 0; k < K_; k++) {
        const int p = pos[2 * n + k];
        if (p >= CAP_) continue;
        const int e = ids[2 * n + k];
        const float w = probs[2 * n + k];
        const ushort4 u = *(const ushort4*)(eo + ((size_t)e * CAP_ + p) * C_ + c);
        r0 = fmaf(w, b2f(u.x), r0); r1 = fmaf(w, b2f(u.y), r1);
        r2 = fmaf(w, b2f(u.z), r2); r3 = fmaf(w, b2f(u.w), r3);
    }
    *(float4*)(y + (size_t)n * C_ + c) = make_float4(r0, r1, r2, r3);
}

// ---------------------------------------------------------------------------
extern "C" void kernel_launch(void* const* d_in, const int* in_sizes, int n_in,
                              void* d_out, int out_size, void* d_ws, size_t ws_size,
                              hipStream_t stream)
{
    const float* x   = (const float*)d_in[0];
    const float* rw1 = (const float*)d_in[1];
    const float* rb1 = (const float*)d_in[2];
    const float* rw2 = (const float*)d_in[3];
    const float* rb2 = (const float*)d_in[4];
    const float* ew1 = (const float*)d_in[5];
    const float* eb1 = (const float*)d_in[6];
    const float* ew2 = (const float*)d_in[7];
    const float* eb2 = (const float*)d_in[8];
    float* y = (float*)d_out;

    // ws layout (<= 384.4 MiB), aliased by liveness:
    //  [0,256MiB)      hexp bf16 [8][4096][4096] (expert GEMM1 out; no h1!)
    //  [256,352MiB)    A2 split-x bf16 [16384][3072] (router) -> later
    //                  disp bf16 [256,320) -> later eo bf16 [256,320)
    //  [320,384MiB)    BTW expert weights (written at 5a, A2/B2/plog dead)
    //  [352,376MiB)    B2 split-w bf16 [4096][3072] (router)
    //  [376,384MiB)    plog f32 [16][16384][8] (router partial logits)
    //  [384MiB,...)    ids / probs / pos (128KiB each)
    char* ws = (char*)d_ws;
    unsigned short* hexp  = (unsigned short*)ws;
    unsigned short* A2    = (unsigned short*)(ws + 268435456L);
    unsigned short* disp  = (unsigned short*)(ws + 268435456L);
    unsigned short* eo    = (unsigned short*)(ws + 268435456L);
    unsigned short* BTW   = (unsigned short*)(ws + 335544320L);
    unsigned short* B2    = (unsigned short*)(ws + 369098752L);
    float*          plog  = (float*)(ws + 394264576L);
    int*            ids   = (int*)  (ws + 402653184L);
    float*          probs = (float*)(ws + 402784256L);
    int*            pos   = (int*)  (ws + 402915328L);

    const size_t LDSB = 131072;   // 128 KiB: 2 dbuf x (A 32K + B 32K)

    // 1a) Build split operands for router GEMM1
    split_x<<<NTOK, 256, 0, stream>>>(x, A2);
    {
        dim3 g(H_ / 32, C_ / 32, 1);
        split_w<<<g, 256, 0, stream>>>(rw1, B2);
    }
    // 1b) Router GEMM1 (split-bf16, ~fp32 exact) + FUSED logits epilogue v2:
    //     plog[bx][n][8] partial logits; h1 never touches HBM.
    {
        dim3 g(H_ / 256, NTOK / 256, 1);   // 16 x 64
        gemm256_8ph<1, float, 3><<<g, 512, LDSB, stream>>>(
            A2, B2, rb1, (float*)nullptr, KR_, H_, KR_ / 64, 0, 0, 0, 0,
            rw2, plog);
    }
    // 2) Deterministic final reduce + top-2 + softmax
    router_topk_final<<<NTOK / 256, 256, 0, stream>>>(plog, rb2, ids, probs);
    // 3) Exact sequential capacity positions
    compute_pos<<<1, 256, 0, stream>>>(ids, pos);
    // 4) Dispatch tokens to expert buffers (bf16) — overwrites A2 (dead)
    dispatch_k<<<NSLOT, 256, 0, stream>>>(x, ids, pos, disp);
    // 5a) Convert+transpose ew1 [8][1024][4096] -> BT1 bf16 [8][4096][1024]
    {
        dim3 g(H_ / 32, C_ / 32, E_);
        transpose_cvt<<<g, 256, 0, stream>>>(ew1, BTW, C_, H_);
    }
    // 5b) Expert GEMM1 (MFMA): hexp = relu(disp @ ew1 + eb1)
    {
        dim3 g(H_ / 256, CAP_ / 256, E_);   // 16 x 16 x 8
        gemm256_8ph<1, unsigned short, 0><<<g, 512, LDSB, stream>>>(
            disp, BTW, eb1, hexp, C_, H_, C_ / 64,
            (long)CAP_ * C_, (long)H_ * C_, (long)H_, (long)CAP_ * H_,
            nullptr, nullptr);
    }
    // 6a) Convert+transpose ew2 [8][4096][1024] -> BT2 bf16 [8][1024][4096]
    {
        dim3 g(C_ / 32, H_ / 32, E_);
        transpose_cvt<<<g, 256, 0, stream>>>(ew2, BTW, H_, C_);
    }
    // 6b) Expert GEMM2 (MFMA): eo = hexp @ ew2 + eb2   (bf16 out; disp dead)
    {
        dim3 g(C_ / 256, CAP_ / 256, E_);   // 4 x 16 x 8
        gemm256_8ph<0, unsigned short, 0><<<g, 512, LDSB, stream>>>(
            hexp, BTW, eb2, eo, H_, C_, H_ / 64,
            (long)CAP_ * H_, (long)C_ * H_, (long)C_, (long)CAP_ * C_,
            nullptr, nullptr);
    }
    // 7) Combine: gather expert outputs, weight, sum (race-free, writes all y)
    combine_k<<<NTOK, 256, 0, stream>>>(eo, ids, pos, probs, y);
}